// Round 13
// baseline (63.316 us; speedup 1.0000x reference)
//
#include <hip/hip_runtime.h>

typedef float __attribute__((ext_vector_type(4))) f32x4;
typedef unsigned int u32;
typedef u32 __attribute__((ext_vector_type(4))) u32x4;

// OUT[n, c=j*8+k, h, w] = sum_{a,m,b} W[j,a,m,b,k] * T[n,(j+a-1)*4+m, (h-1)%28, (w+b-2)%28]
//   T[n,cc,h,w] = x[n,cc,h,w] + x[n,cc+128,h,w]
//   (j+a-1) outside [0,32) -> zero; (w+b-1) outside [0,28) -> zero (w unfold pad)
//
// R13: 8 block-contexts per CU. Context-count evidence: 2 ctx (R10, 54.1) -> 4 ctx
//   (R11, 50.3); wave-cap blocks 512-thread blocks at 4/CU. Here: 1-row 256-thread
//   blocks with TOTAL LDS = 8.2 KB (output rounds REUSE the input buffer) ->
//   __launch_bounds__(256,8) -> 8 blocks/CU = 32 waves in 8 independent contexts.
// Output tail is R10/R11-style block-wide rounds (R12's wave-autonomous tail regressed:
//   divergent dump + full-wave lgkmcnt stalls). Dump wave is uniform (tid>>6 == c).
// Verified pieces byte-for-byte: bf16-pair m-packed LDS + v_dot2_f32_bf16 compute
//   (absmax 0.5, R7/R9/R10/R11), quad-slot swizzle slot=q^(g&7) (R2: 0 conflicts;
//   1-row staging writes only slots {0..6}^sw and compute reads exactly those).

__device__ __forceinline__ u32 pack2bf(float lo, float hi) {
    u32 a = __float_as_uint(lo), b = __float_as_uint(hi);
    a = (a + 0x7FFFu + ((a >> 16) & 1u)) >> 16;   // RNE round to bf16
    b = (b + 0x7FFFu + ((b >> 16) & 1u)) >> 16;
    return a | (b << 16);
}

__device__ __forceinline__ float dot2bf(u32 t2, u32 w2, float acc) {
    asm("v_dot2_f32_bf16 %0, %1, %2, %0" : "+v"(acc) : "v"(t2), "v"(w2));
    return acc;
}

__global__ __launch_bounds__(256, 8) void fused_shift_conv(
    const float* __restrict__ x, const float* __restrict__ Wt, float* __restrict__ out)
{
    __shared__ __align__(16) u32 L[2048];   // 8 KB: input bf16; reused as out f32 buffer

    const int tid = threadIdx.x;
    const int R   = blockIdx.x;             // global row n*28 + h
    const int n   = R / 28;
    const int h   = R - n * 28;
    const int h_src = (h + 27) % 28;        // roll(+1) along h

    const float* xn = x + (size_t)n * 200704 + h_src * 28;

    // ---- staging: 64 ch-pairs x 7 quads = 448 items; lanes walk q within a pair ----
    #pragma unroll
    for (int it = 0; it < 2; ++it) {
        const int f = tid + it * 256;
        if (f < 448) {
            const int p = f / 7;            // channel pair 0..63 (ch 2p, 2p+1)
            const int q = f - p * 7;        // quad 0..6
            const float* b0 = xn + (2 * p) * 784 + q * 4;
            const f32x4 l0 = *(const f32x4*)b0;                  // ch 2p,   low half
            const f32x4 l1 = *(const f32x4*)(b0 + 784);          // ch 2p+1, low half
            const f32x4 u0 = *(const f32x4*)(b0 + 100352);       // high halves
            const f32x4 u1 = *(const f32x4*)(b0 + 784 + 100352);
            const f32x4 s0 = l0 + u0, s1 = l1 + u1;
            u32x4 wv;
            #pragma unroll
            for (int e = 0; e < 4; ++e) wv[e] = pack2bf(s0[e], s1[e]);
            const int sw = (p >> 1) & 7;    // g = p>>1
            *(u32x4*)&L[p * 32 + ((q ^ sw) << 2)] = wv;
        }
    }

    // ---- per-thread weights: thread owns channel c = tid = j*8+k ----
    const int j = tid >> 3, k = tid & 7;
    u32 w2[3][2][3];                        // [a][m-pair][tap], bf16-pair packed
    {
        const float* wp = Wt + j * 288 + k; // W[j,a,m,b,k] strides 288/96/24/8/1
        #pragma unroll
        for (int a = 0; a < 3; ++a)
            #pragma unroll
            for (int m2 = 0; m2 < 2; ++m2)
                #pragma unroll
                for (int bb = 0; bb < 3; ++bb)
                    w2[a][m2][bb] = pack2bf(wp[a*96 + (2*m2  )*24 + bb*8],
                                            wp[a*96 + (2*m2+1)*24 + bb*8]);
    }
    if (j == 0) {
        #pragma unroll
        for (int m2 = 0; m2 < 2; ++m2)
            #pragma unroll
            for (int bb = 0; bb < 3; ++bb) w2[0][m2][bb] = 0u;
    }
    if (j == 31) {
        #pragma unroll
        for (int m2 = 0; m2 < 2; ++m2)
            #pragma unroll
            for (int bb = 0; bb < 3; ++bb) w2[2][m2][bb] = 0u;
    }

    // ---- hoisted output readback indices (round-invariant) ----
    const int f0 = tid;                     // item: chl = f/7, q = f%7 (f < 448)
    const int c0 = f0 / 7, q0 = f0 - c0 * 7;
    const int f1 = tid + 256;
    const int c1 = f1 / 7, q1 = f1 - c1 * 7;
    const bool has1 = (f1 < 448);

    __syncthreads();

    // ---- compute (verified body): 42 ds_read_b128 + ~492 dot2 ----
    float acc[28];
    #pragma unroll
    for (int w = 0; w < 28; ++w) acc[w] = 0.f;

    #pragma unroll
    for (int a = 0; a < 3; ++a) {
        int g = j + a - 1;
        g = g < 0 ? 0 : (g > 31 ? 31 : g);  // weights already zeroed for OOB
        const int s = g & 7;
        #pragma unroll
        for (int m2 = 0; m2 < 2; ++m2) {
            const int rowd = (g * 2 + m2) * 32;
            const u32 t2 = w2[a][m2][2], t1 = w2[a][m2][1], t0 = w2[a][m2][0];
            #pragma unroll
            for (int qb = 0; qb < 7; ++qb) {
                const u32x4 v = *(const u32x4*)&L[rowd + ((qb ^ s) << 2)];
                #pragma unroll
                for (int e = 0; e < 4; ++e) {
                    const int wp_ = qb * 4 + e;                              // source col w'
                    if (wp_ != 27) acc[wp_] = dot2bf(v[e], t2, acc[wp_]);    // b=2 tap
                    acc[(wp_ + 1) % 28] = dot2bf(v[e], t1, acc[(wp_ + 1) % 28]); // b=1
                    if (wp_ != 26) acc[(wp_ + 2) % 28] = dot2bf(v[e], t0, acc[(wp_ + 2) % 28]); // b=0
                }
            }
        }
    }

    // ---- output: 4 rounds of 64 channels via LDS (reuses input region) ----
    float* Lf = (float*)L;                  // [64 ch][pitch 29] = 7424 f <= 8192
    float* outn = out + (size_t)n * 200704 + h * 28;
    #pragma unroll
    for (int c = 0; c < 4; ++c) {
        __syncthreads();                    // compute / prev-round reads done
        if ((tid >> 6) == c) {              // wave c: uniform dump of its 64 channels
            float* dst = Lf + (tid & 63) * 29;
            #pragma unroll
            for (int qq = 0; qq < 7; ++qq) {
                f32x4 o;
                o.x = acc[qq * 4 + 0];
                o.y = acc[qq * 4 + 1];
                o.z = acc[qq * 4 + 2];
                o.w = acc[qq * 4 + 3];
                *(f32x4*)(dst + qq * 4) = o;
            }
        }
        __syncthreads();
        {
            const f32x4 v = *(const f32x4*)(Lf + c0 * 29 + q0 * 4);
            *(f32x4*)(outn + (size_t)(c * 64 + c0) * 784 + q0 * 4) = v;
        }
        if (has1) {
            const f32x4 v = *(const f32x4*)(Lf + c1 * 29 + q1 * 4);
            *(f32x4*)(outn + (size_t)(c * 64 + c1) * 784 + q1 * 4) = v;
        }
    }
}

extern "C" void kernel_launch(void* const* d_in, const int* in_sizes, int n_in,
                              void* d_out, int out_size, void* d_ws, size_t ws_size,
                              hipStream_t stream) {
    const float* x  = (const float*)d_in[0];   // (128,256,28,28) f32
    const float* Wt = (const float*)d_in[1];   // (32,3,4,3,8)   f32
    float* out      = (float*)d_out;           // (128,256,28,28) f32

    const int nbatch = in_sizes[0] / 200704;   // 128
    fused_shift_conv<<<nbatch * 28, 256, 0, stream>>>(x, Wt, out);  // 1 row per block
}

// Round 14
// 50.367 us; speedup vs baseline: 1.2571x; 1.2571x over previous
//
#include <hip/hip_runtime.h>

typedef float __attribute__((ext_vector_type(4))) f32x4;
typedef unsigned int u32;
typedef u32 __attribute__((ext_vector_type(4))) u32x4;

// OUT[n, c=j*8+k, h, w] = sum_{a,m,b} W[j,a,m,b,k] * T[n,(j+a-1)*4+m, (h-1)%28, (w+b-2)%28]
//   T[n,cc,h,w] = x[n,cc,h,w] + x[n,cc+128,h,w]
//   (j+a-1) outside [0,32) -> zero; (w+b-1) outside [0,28) -> zero (w unfold pad)
//
// R14: 8 phase-contexts/CU with 224B store runs preserved (fixing R13's mistake).
//   Block = (n, h-pair, channel-half): 256 threads handle j in [J0,J0+16) for rows
//   h0,h0+1. Input window = groups J0-1..J0+16 (18 groups, 36 pairs, 12.5% overlap
//   between halves -> L2/L3-absorbed). LDS = 15.4 KB (input 9.2 KB, tail reuses) ->
//   thread-cap 8 blocks/CU = 32 waves in 8 independent contexts (2x R11).
//   Tail: 2 rounds x 64 ch, 224 B contiguous stores (R11-style, NOT R13's 112 B).
// Verified pieces: bf16-pair m-packed LDS + v_dot2_f32_bf16 (absmax 0.5 since R7),
//   swizzle slot=q^(gl&7) (8 consecutive gl per wave -> conflict-free, R2-lineage),
//   OOB groups ZERO-FILLED in LDS (garbage would make 0*NaN = NaN).

__device__ __forceinline__ u32 pack2bf(float lo, float hi) {
    u32 a = __float_as_uint(lo), b = __float_as_uint(hi);
    a = (a + 0x7FFFu + ((a >> 16) & 1u)) >> 16;   // RNE round to bf16
    b = (b + 0x7FFFu + ((b >> 16) & 1u)) >> 16;
    return a | (b << 16);
}

__device__ __forceinline__ float dot2bf(u32 t2, u32 w2, float acc) {
    asm("v_dot2_f32_bf16 %0, %1, %2, %0" : "+v"(acc) : "v"(t2), "v"(w2));
    return acc;
}

__global__ __launch_bounds__(256, 8) void fused_shift_conv(
    const float* __restrict__ x, const float* __restrict__ Wt, float* __restrict__ out)
{
    __shared__ __align__(16) u32 L[3840];   // 15 KB: input 2x1152 dw; tail reuses [64][60]

    const int tid  = threadIdx.x;
    const int blk  = blockIdx.x;
    const int half = blk & 1;               // channel half: j in [J0, J0+16)
    const int rest = blk >> 1;
    const int n    = rest / 14;
    const int b2   = rest - n * 14;
    const int h0   = b2 * 2;                // output rows h0, h0+1
    const int J0   = half * 16;

    const float* xn = x + (size_t)n * 200704;

    // ---- staging: 36 local pairs x 2 rows x 7 quads = 504 items, 224 B runs ----
    #pragma unroll
    for (int it = 0; it < 2; ++it) {
        const int f = tid + it * 256;
        if (f < 504) {
            const int pl  = f / 14;         // local pair 0..35
            const int rem = f - pl * 14;
            const int row = rem / 7;        // input row 0..1
            const int q   = rem - row * 7;  // quad 0..6
            const int gl  = pl >> 1;        // local group 0..17
            const int mp  = pl & 1;
            const int g   = J0 - 1 + gl;    // global group -1..32
            int hs = h0 - 1 + row;          // wraps only when h0==0 && row==0
            hs = hs < 0 ? 27 : hs;
            u32x4 wv = {0u, 0u, 0u, 0u};    // OOB groups -> zeros (NaN-safe)
            if (g >= 0 && g <= 31) {
                const int ch0 = g * 4 + mp * 2;
                const float* b0 = xn + ch0 * 784 + hs * 28 + q * 4;
                const f32x4 l0 = *(const f32x4*)b0;                  // ch0, low half
                const f32x4 l1 = *(const f32x4*)(b0 + 784);          // ch0+1, low half
                const f32x4 u0 = *(const f32x4*)(b0 + 100352);       // high halves
                const f32x4 u1 = *(const f32x4*)(b0 + 784 + 100352);
                const f32x4 s0 = l0 + u0, s1 = l1 + u1;
                #pragma unroll
                for (int e = 0; e < 4; ++e) wv[e] = pack2bf(s0[e], s1[e]);
            }
            const int sw = gl & 7;
            *(u32x4*)&L[row * 1152 + pl * 32 + ((q ^ sw) << 2)] = wv;
        }
    }

    // ---- per-thread weights: thread (s_=tid>>7, tloc=tid&127) owns c = j*8+k ----
    const int tloc = tid & 127;
    const int s_   = tid >> 7;              // which output row (h0 + s_)
    const int jl   = tloc >> 3;             // 0..15
    const int j    = J0 + jl;
    const int k    = tloc & 7;
    u32 w2[3][2][3];                        // [a][m-pair][tap], bf16-pair packed
    {
        const float* wp = Wt + j * 288 + k; // W[j,a,m,b,k] strides 288/96/24/8/1
        #pragma unroll
        for (int a = 0; a < 3; ++a)
            #pragma unroll
            for (int m2 = 0; m2 < 2; ++m2)
                #pragma unroll
                for (int bb = 0; bb < 3; ++bb)
                    w2[a][m2][bb] = pack2bf(wp[a*96 + (2*m2  )*24 + bb*8],
                                            wp[a*96 + (2*m2+1)*24 + bb*8]);
    }
    if (j == 0) {
        #pragma unroll
        for (int m2 = 0; m2 < 2; ++m2)
            #pragma unroll
            for (int bb = 0; bb < 3; ++bb) w2[0][m2][bb] = 0u;
    }
    if (j == 31) {
        #pragma unroll
        for (int m2 = 0; m2 < 2; ++m2)
            #pragma unroll
            for (int bb = 0; bb < 3; ++bb) w2[2][m2][bb] = 0u;
    }

    // ---- hoisted tail readback indices (round-invariant) ----
    // round: 64 ch x 14 f4 = 896 items; 4 iterations of 256 (3.5 used)
    int rb_c[4], rb_r[4];
    #pragma unroll
    for (int it = 0; it < 4; ++it) {
        const int fo = tid + it * 256;
        rb_c[it] = fo / 14;                 // local channel 0..63
        rb_r[it] = fo - rb_c[it] * 14;      // f4 within 224 B run
    }

    __syncthreads();

    // ---- compute (verified body): 42 ds_read_b128 + ~492 dot2 ----
    const u32* Bs = L + s_ * 1152;
    float acc[28];
    #pragma unroll
    for (int w = 0; w < 28; ++w) acc[w] = 0.f;

    #pragma unroll
    for (int a = 0; a < 3; ++a) {
        const int gl = jl + a;              // 0..17, always in window
        const int s  = gl & 7;
        #pragma unroll
        for (int m2 = 0; m2 < 2; ++m2) {
            const int rowd = (gl * 2 + m2) * 32;
            const u32 t2 = w2[a][m2][2], t1 = w2[a][m2][1], t0 = w2[a][m2][0];
            #pragma unroll
            for (int qb = 0; qb < 7; ++qb) {
                const u32x4 v = *(const u32x4*)&Bs[rowd + ((qb ^ s) << 2)];
                #pragma unroll
                for (int e = 0; e < 4; ++e) {
                    const int wp_ = qb * 4 + e;                              // source col w'
                    if (wp_ != 27) acc[wp_] = dot2bf(v[e], t2, acc[wp_]);    // b=2 tap
                    acc[(wp_ + 1) % 28] = dot2bf(v[e], t1, acc[(wp_ + 1) % 28]); // b=1
                    if (wp_ != 26) acc[(wp_ + 2) % 28] = dot2bf(v[e], t0, acc[(wp_ + 2) % 28]); // b=0
                }
            }
        }
    }

    // ---- output: 2 rounds of 64 channels via LDS, contiguous 224 B stores ----
    float* Lf = (float*)L;                  // input region dead after compute
    float* outb = out + (size_t)n * 200704 + (size_t)(J0 * 8) * 784 + h0 * 28;
    #pragma unroll
    for (int c = 0; c < 2; ++c) {
        __syncthreads();                    // compute / prev-round reads done
        if ((tloc >> 6) == c) {             // 128 owner threads (64 ch x 2 rows) dump
            float* dst = Lf + (tloc & 63) * 60 + s_ * 28;
            #pragma unroll
            for (int qq = 0; qq < 7; ++qq) {
                f32x4 o;
                o.x = acc[qq * 4 + 0];
                o.y = acc[qq * 4 + 1];
                o.z = acc[qq * 4 + 2];
                o.w = acc[qq * 4 + 3];
                *(f32x4*)(dst + qq * 4) = o;
            }
        }
        __syncthreads();
        float* outc = outb + (size_t)(c * 64) * 784;
        #pragma unroll
        for (int it = 0; it < 4; ++it) {
            if (tid + it * 256 < 896) {
                const f32x4 v = *(const f32x4*)(Lf + rb_c[it] * 60 + rb_r[it] * 4);
                *(f32x4*)(outc + (size_t)rb_c[it] * 784 + rb_r[it] * 4) = v;
            }
        }
    }
}

extern "C" void kernel_launch(void* const* d_in, const int* in_sizes, int n_in,
                              void* d_out, int out_size, void* d_ws, size_t ws_size,
                              hipStream_t stream) {
    const float* x  = (const float*)d_in[0];   // (128,256,28,28) f32
    const float* Wt = (const float*)d_in[1];   // (32,3,4,3,8)   f32
    float* out      = (float*)d_out;           // (128,256,28,28) f32

    const int nbatch = in_sizes[0] / 200704;   // 128
    // grid: (n, h-pair, channel-half) -> 128*14*2 = 3584 blocks
    fused_shift_conv<<<nbatch * 28, 256, 0, stream>>>(x, Wt, out);
}